// Round 5
// baseline (311.059 us; speedup 1.0000x reference)
//
#include <hip/hip_runtime.h>
#include <hip/hip_bf16.h>

// VecLocal2d: x[320][32][32][32] f32, weight[32][32][64][288] f32, bias[10][64][1024] f32
// out[320][64][1024] f32.  Per (h,w): out[m,o] = sum_k patch[m,k]*W[o,k] + bias.
//
// R3: k permuted to k' = (dy*3+dx)*32 + c, x transposed to xT2[yx][m][c] bf16.
// A-fragments are direct 16B global loads; weight staged once to LDS; B-frags in VGPRs.
// R4 (measured): A-load batching was NEUTRAL-NEGATIVE (62->65us, occ 35->18%, same BW)
//   -> main is NOT latency-bound; reverted to R3 interleaved inner loop.
// R5 (resubmit after infra timeout): fuse outT into main. main stores directly to
//   out[(m*64+o)*1024+loc] (4B/lane scatter) with bias added from LDS. Each 64B out
//   line = 16 w-adjacent locs; bid remapped so each 16-loc group occupies ONE XCD
//   (bid&7 = xcd, consecutive slots) so the 16 partial line writes merge in that XCD's
//   L2. Removes outT kernel + 168 MB of out_s round-trip traffic.
//   Diagnostic: WRITE_SIZE ~84-100MB = merged; >=200MB = amplified.

typedef __attribute__((ext_vector_type(8))) short short8;
typedef __attribute__((ext_vector_type(4))) float f32x4;
typedef __attribute__((ext_vector_type(4))) unsigned short ushort4b;

#define XT2_ELEMS 10485760             // 1024 yx * 320 m * 32 c
#define ZSLAB_ELEMS 10240              // 320 m * 32 c zero slab for OOB taps

__device__ __forceinline__ unsigned short f2bf(float f) {
    __hip_bfloat16 b = __float2bfloat16(f);
    return __builtin_bit_cast(unsigned short, b);
}

// ---- kernel 1: x[mc][yx] f32 -> xT2[yx][mc] bf16  (10240 x 1024 transpose)
__global__ __launch_bounds__(256) void VecLocal2d_xpose(const float* __restrict__ x,
                                                        unsigned short* __restrict__ xT2) {
    __shared__ unsigned short tile[64][68];  // row = 136 B (8B-aligned for b64 writes)
    if (blockIdx.x == 0) {  // zero slab for out-of-bounds patch taps
#pragma unroll
        for (int j = 0; j < 20; ++j)
            reinterpret_cast<unsigned int*>(xT2 + XT2_ELEMS)[threadIdx.x + j * 256] = 0u;
    }
    const int mcb = blockIdx.x >> 4;   // 160 tiles over mc
    const int yxb = blockIdx.x & 15;   // 16 tiles over yx
    const int t = threadIdx.x;
    const int g = t >> 4;              // 0..15
    const int l4 = (t & 15) * 4;
#pragma unroll
    for (int p = 0; p < 4; ++p) {
        const int ml = g + p * 16;     // mc-local row
        const float4 v = *reinterpret_cast<const float4*>(
            x + (size_t)(mcb * 64 + ml) * 1024 + yxb * 64 + l4);
        ushort4b u;
        u.x = f2bf(v.x); u.y = f2bf(v.y); u.z = f2bf(v.z); u.w = f2bf(v.w);
        *reinterpret_cast<ushort4b*>(&tile[ml][l4]) = u;
    }
    __syncthreads();
#pragma unroll
    for (int p = 0; p < 4; ++p) {
        const int yl = g + p * 16;     // yx-local row
        ushort4b u;
        u.x = tile[l4 + 0][yl];
        u.y = tile[l4 + 1][yl];
        u.z = tile[l4 + 2][yl];
        u.w = tile[l4 + 3][yl];
        *reinterpret_cast<ushort4b*>(xT2 + (size_t)(yxb * 64 + yl) * 10240 + mcb * 64 + l4) = u;
    }
}

// ---- kernel 2: main GEMM per location; writes FINAL layout (bias fused), no out_s.
__global__ __launch_bounds__(256, 3) void VecLocal2d_main(const unsigned short* __restrict__ xT2,
                                                          const float* __restrict__ weight,
                                                          const float* __restrict__ bias,
                                                          float* __restrict__ out) {
    __shared__ unsigned short wLDS[64 * 296];  // [o][k'], k' = (dy*3+dx)*32 + c, pad->296
    __shared__ float biasLDS[10 * 65];         // [cat][o], padded row 65 to spread banks

    // R5 loc mapping: 64 groups of 16 w-adjacent locs; group g -> XCD g&7 entirely
    // (bid&7 = xcd under round-robin dispatch), 16 members in consecutive slots on
    // that XCD so their partial out-line writes merge in its L2.
    const int bid = blockIdx.x;
    const int xcd = bid & 7;
    const int i = bid >> 3;            // 0..127
    const int slot = i >> 4;           // 0..7
    const int k16 = i & 15;            // member within group
    const int grp = slot * 8 + xcd;    // 0..63
    const int loc = grp * 16 + k16;    // = h*32 + w
    const int h = loc >> 5;
    const int w = loc & 31;

    const int tid = threadIdx.x;
    const int lane = tid & 63;
    const int wave = tid >> 6;
    const int quad = lane >> 4;
    const int l16 = lane & 15;
    const int wm = wave >> 1, wn = wave & 1;  // 2x2 wave grid over (m32, o32)

    // ---- stage weight (64*288 f32, contiguous reads) -> wLDS bf16, k-permuted ----
    const float* wg = weight + (size_t)loc * 18432;
#pragma unroll
    for (int i2 = 0; i2 < 18; ++i2) {
        const int f4i = tid + i2 * 256;
        const float4 v = reinterpret_cast<const float4*>(wg)[f4i];
        const int o = f4i / 72;
        const int kbase = (f4i - o * 72) * 4;
        const float vv[4] = {v.x, v.y, v.z, v.w};
#pragma unroll
        for (int e = 0; e < 4; ++e) {
            const int k = kbase + e;       // original k = c*9 + r
            const int c = k / 9;
            const int r = k - c * 9;
            wLDS[o * 296 + r * 32 + c] = f2bf(vv[e]);
        }
    }

    // ---- stage bias slice for this loc: bias[cat][o][loc], 640 f32 ----
    for (int i2 = tid; i2 < 640; i2 += 256) {
        const int cat = i2 >> 6;
        const int o = i2 & 63;
        biasLDS[cat * 65 + o] = bias[((size_t)(cat * 64 + o)) * 1024 + loc];
    }

    // ---- 9 neighbor base offsets (block-uniform -> SGPRs); OOB -> zero slab ----
    int base[9];
#pragma unroll
    for (int dy = 0; dy < 3; ++dy)
#pragma unroll
        for (int dx = 0; dx < 3; ++dx) {
            const int y = h - 1 + dy;
            const int xc = w - 1 + dx;
            const bool valid = ((unsigned)y < 32u) && ((unsigned)xc < 32u);
            base[dy * 3 + dx] = valid ? (y * 32 + xc) * 10240 : XT2_ELEMS;
        }

    __syncthreads();

    // ---- B-fragments in registers for the whole m-loop (weight read once) ----
    short8 bfr[2][9];
#pragma unroll
    for (int tni = 0; tni < 2; ++tni) {
        const int o = (wn * 2 + tni) * 16 + l16;
#pragma unroll
        for (int kt = 0; kt < 9; ++kt)
            bfr[tni][kt] = *reinterpret_cast<const short8*>(&wLDS[o * 296 + kt * 32 + quad * 8]);
    }

    const int laneA = (wm * 32 + l16) * 32 + quad * 8;  // + tmi*512 + mt*2048
    // per-(tmi) m-base and its %10 (for cat chains): mbase = wm*32 + tmi*16 + quad*4
    const int mb0 = wm * 32 + quad * 4;          // tmi=0
    const int cat0_0 = mb0 % 10;
    const int cat0_1 = (mb0 + 16) % 10;

    for (int mt = 0; mt < 5; ++mt) {
        const int moff = laneA + mt * 2048;
        f32x4 acc[2][2] = {};
#pragma unroll
        for (int kt = 0; kt < 9; ++kt) {
            const short8 a0 = *reinterpret_cast<const short8*>(xT2 + base[kt] + moff);
            const short8 a1 = *reinterpret_cast<const short8*>(xT2 + base[kt] + moff + 512);
            acc[0][0] = __builtin_amdgcn_mfma_f32_16x16x32_bf16(a0, bfr[0][kt], acc[0][0], 0, 0, 0);
            acc[0][1] = __builtin_amdgcn_mfma_f32_16x16x32_bf16(a0, bfr[1][kt], acc[0][1], 0, 0, 0);
            acc[1][0] = __builtin_amdgcn_mfma_f32_16x16x32_bf16(a1, bfr[0][kt], acc[1][0], 0, 0, 0);
            acc[1][1] = __builtin_amdgcn_mfma_f32_16x16x32_bf16(a1, bfr[1][kt], acc[1][1], 0, 0, 0);
        }

        // D layout: row m = quad*4 + r (within 16-tile), col o = l16.
        // R5: direct scatter store to out[(m*64+o)*1024 + loc] with fused bias.
        const int mt4 = mt * 4;  // 64 % 10 == 4: cat advances by 4 per mt
#pragma unroll
        for (int tmi = 0; tmi < 2; ++tmi) {
            const int mbase = mt * 64 + (wm * 2 + tmi) * 16 + quad * 4;
            const int cbase = (tmi ? cat0_1 : cat0_0) + mt4;  // <= 9+16
#pragma unroll
            for (int tni = 0; tni < 2; ++tni) {
                const int o = (wn * 2 + tni) * 16 + l16;
#pragma unroll
                for (int r = 0; r < 4; ++r) {
                    int cat = cbase + r;                  // <= 28
                    cat -= (cat >= 20) ? 20 : ((cat >= 10) ? 10 : 0);
                    const float v = acc[tmi][tni][r] + biasLDS[cat * 65 + o];
                    out[((size_t)((mbase + r) * 64 + o)) * 1024 + loc] = v;
                }
            }
        }
    }
}

extern "C" void kernel_launch(void* const* d_in, const int* in_sizes, int n_in,
                              void* d_out, int out_size, void* d_ws, size_t ws_size,
                              hipStream_t stream) {
    const float* x = (const float*)d_in[0];
    const float* wgt = (const float*)d_in[1];
    const float* bias = (const float*)d_in[2];
    float* out = (float*)d_out;
    unsigned short* xT2 = (unsigned short*)d_ws;   // 21.0 MB (+20KB zero slab)

    VecLocal2d_xpose<<<2560, 256, 0, stream>>>(x, xT2);
    VecLocal2d_main<<<1024, 256, 0, stream>>>(xT2, wgt, bias, out);
}

// Round 8
// 225.606 us; speedup vs baseline: 1.3788x; 1.3788x over previous
//
#include <hip/hip_runtime.h>
#include <hip/hip_bf16.h>

// VecLocal2d: x[320][32][32][32] f32, weight[32][32][64][288] f32, bias[10][64][1024] f32
// out[320][64][1024] f32.  Per (h,w): out[m,o] = sum_k patch[m,k]*W[o,k] + bias.
//
// R3: k permuted to k' = (dy*3+dx)*32 + c, x transposed to xT2[yx][m][c] bf16.
// A-fragments are direct 16B global loads; weight staged once to LDS; B-frags in VGPRs.
// R4 (measured): A-load batching NEUTRAL-NEGATIVE (62->65us) -> not latency-bound.
// R5 (measured): outT-fusion via 4B scatter stores FAILED: WRITE_SIZE 84->215MB (2.5x
//   amplification, L2 didn't merge partial lines), main 62->180us. out_s+outT restored.
// R6 (third submit; two infra timeouts, never measured): R3 structure + MFMA OPERAND
//   SWAP: acc = mfma(Wfrag, Xfrag, acc) -> D comes out [o-rows][m-cols]: lane holds 4
//   CONSECUTIVE o per reg quad, so the epilogue is 20 dwordx4 stores/thread instead of
//   80 scalar dword stores (4x fewer store instrs in the vmcnt FIFO ahead of next-mt
//   loads). Same out_s layout; outT unchanged. Tests the store-FIFO hypothesis for
//   main's 62us (roofline ~30us).

typedef __attribute__((ext_vector_type(8))) short short8;
typedef __attribute__((ext_vector_type(4))) float f32x4;
typedef __attribute__((ext_vector_type(4))) unsigned short ushort4b;

#define XT2_ELEMS 10485760             // 1024 yx * 320 m * 32 c
#define ZSLAB_ELEMS 10240              // 320 m * 32 c zero slab for OOB taps
#define OUTS_OFF_BYTES 20992000        // (XT2_ELEMS + ZSLAB_ELEMS)*2 = 20,992,000 B

__device__ __forceinline__ unsigned short f2bf(float f) {
    __hip_bfloat16 b = __float2bfloat16(f);
    return __builtin_bit_cast(unsigned short, b);
}

// ---- kernel 1: x[mc][yx] f32 -> xT2[yx][mc] bf16  (10240 x 1024 transpose)
__global__ __launch_bounds__(256) void VecLocal2d_xpose(const float* __restrict__ x,
                                                        unsigned short* __restrict__ xT2) {
    __shared__ unsigned short tile[64][68];  // row = 136 B (8B-aligned for b64 writes)
    if (blockIdx.x == 0) {  // zero slab for out-of-bounds patch taps
#pragma unroll
        for (int j = 0; j < 20; ++j)
            reinterpret_cast<unsigned int*>(xT2 + XT2_ELEMS)[threadIdx.x + j * 256] = 0u;
    }
    const int mcb = blockIdx.x >> 4;   // 160 tiles over mc
    const int yxb = blockIdx.x & 15;   // 16 tiles over yx
    const int t = threadIdx.x;
    const int g = t >> 4;              // 0..15
    const int l4 = (t & 15) * 4;
#pragma unroll
    for (int p = 0; p < 4; ++p) {
        const int ml = g + p * 16;     // mc-local row
        const float4 v = *reinterpret_cast<const float4*>(
            x + (size_t)(mcb * 64 + ml) * 1024 + yxb * 64 + l4);
        ushort4b u;
        u.x = f2bf(v.x); u.y = f2bf(v.y); u.z = f2bf(v.z); u.w = f2bf(v.w);
        *reinterpret_cast<ushort4b*>(&tile[ml][l4]) = u;
    }
    __syncthreads();
#pragma unroll
    for (int p = 0; p < 4; ++p) {
        const int yl = g + p * 16;     // yx-local row
        ushort4b u;
        u.x = tile[l4 + 0][yl];
        u.y = tile[l4 + 1][yl];
        u.z = tile[l4 + 2][yl];
        u.w = tile[l4 + 3][yl];
        *reinterpret_cast<ushort4b*>(xT2 + (size_t)(yxb * 64 + yl) * 10240 + mcb * 64 + l4) = u;
    }
}

// ---- kernel 2: main GEMM per location; A-frags straight from global, no inner barriers
__global__ __launch_bounds__(256, 4) void VecLocal2d_main(const unsigned short* __restrict__ xT2,
                                                          const float* __restrict__ weight,
                                                          float* __restrict__ out_s) {
    __shared__ unsigned short wLDS[64 * 296];  // [o][k'], k' = (dy*3+dx)*32 + c, pad->296

    // XCD swizzle: neighbors in (h,w) share XCD for xT2 L2 reuse.
    const int bid = blockIdx.x;
    const int s = bid >> 7;
    const int hg = bid & 127;
    const int h = hg >> 2;
    const int w = ((hg & 3) << 3) | s;
    const int loc = h * 32 + w;

    const int tid = threadIdx.x;
    const int lane = tid & 63;
    const int wave = tid >> 6;
    const int quad = lane >> 4;
    const int l16 = lane & 15;
    const int wm = wave >> 1, wn = wave & 1;  // 2x2 wave grid over (m32, o32)

    // ---- stage weight (64*288 f32, contiguous reads) -> wLDS bf16, k-permuted ----
    const float* wg = weight + (size_t)loc * 18432;
#pragma unroll
    for (int i = 0; i < 18; ++i) {
        const int f4i = tid + i * 256;
        const float4 v = reinterpret_cast<const float4*>(wg)[f4i];
        const int o = f4i / 72;
        const int kbase = (f4i - o * 72) * 4;
        const float vv[4] = {v.x, v.y, v.z, v.w};
#pragma unroll
        for (int e = 0; e < 4; ++e) {
            const int k = kbase + e;       // original k = c*9 + r
            const int c = k / 9;
            const int r = k - c * 9;
            wLDS[o * 296 + r * 32 + c] = f2bf(vv[e]);
        }
    }

    // ---- 9 neighbor base offsets (block-uniform -> SGPRs); OOB -> zero slab ----
    int base[9];
#pragma unroll
    for (int dy = 0; dy < 3; ++dy)
#pragma unroll
        for (int dx = 0; dx < 3; ++dx) {
            const int y = h - 1 + dy;
            const int xc = w - 1 + dx;
            const bool valid = ((unsigned)y < 32u) && ((unsigned)xc < 32u);
            base[dy * 3 + dx] = valid ? (y * 32 + xc) * 10240 : XT2_ELEMS;
        }

    __syncthreads();

    // ---- W-fragments in registers for the whole m-loop (weight read once) ----
    short8 bfr[2][9];
#pragma unroll
    for (int tni = 0; tni < 2; ++tni) {
        const int o = (wn * 2 + tni) * 16 + l16;
#pragma unroll
        for (int kt = 0; kt < 9; ++kt)
            bfr[tni][kt] = *reinterpret_cast<const short8*>(&wLDS[o * 296 + kt * 32 + quad * 8]);
    }

    const int laneA = (wm * 32 + l16) * 32 + quad * 8;  // + tmi*512 + mt*2048
    float* os = out_s + (size_t)loc * 20480;

    for (int mt = 0; mt < 5; ++mt) {
        const int moff = laneA + mt * 2048;
        f32x4 acc[2][2] = {};
#pragma unroll
        for (int kt = 0; kt < 9; ++kt) {
            const short8 a0 = *reinterpret_cast<const short8*>(xT2 + base[kt] + moff);
            const short8 a1 = *reinterpret_cast<const short8*>(xT2 + base[kt] + moff + 512);
            // R6: operands swapped -> D[o_rows][m_cols]; acc[tmi] still indexes m-half.
            acc[0][0] = __builtin_amdgcn_mfma_f32_16x16x32_bf16(bfr[0][kt], a0, acc[0][0], 0, 0, 0);
            acc[0][1] = __builtin_amdgcn_mfma_f32_16x16x32_bf16(bfr[1][kt], a0, acc[0][1], 0, 0, 0);
            acc[1][0] = __builtin_amdgcn_mfma_f32_16x16x32_bf16(bfr[0][kt], a1, acc[1][0], 0, 0, 0);
            acc[1][1] = __builtin_amdgcn_mfma_f32_16x16x32_bf16(bfr[1][kt], a1, acc[1][1], 0, 0, 0);
        }

        // Swapped-D layout: col (=m_local) = l16, row (=o_local) = quad*4 + reg.
        // Lane holds 4 CONSECUTIVE o for one m -> one dwordx4 store per (tmi,tni).
#pragma unroll
        for (int tmi = 0; tmi < 2; ++tmi) {
            const int m = mt * 64 + wm * 32 + tmi * 16 + l16;
#pragma unroll
            for (int tni = 0; tni < 2; ++tni) {
                const int ob = (wn * 2 + tni) * 16 + quad * 4;
                *reinterpret_cast<f32x4*>(&os[m * 64 + ob]) = acc[tmi][tni];
            }
        }
    }
}

// ---- kernel 3: out_s[loc][m*64+o] -> out[(m*64+o)*1024+loc], bias fused.
__global__ __launch_bounds__(256) void VecLocal2d_outT(const float* __restrict__ out_s,
                                                       const float* __restrict__ bias,
                                                       float* __restrict__ out) {
    __shared__ float tile[64][65];
    const int m = blockIdx.x >> 4;
    const int loc0 = (blockIdx.x & 15) * 64;
    const int t = threadIdx.x;
    const float* src = out_s + (size_t)loc0 * 20480 + m * 64;
#pragma unroll
    for (int p = 0; p < 4; ++p) {
        const int idx = p * 256 + t;
        const int lr = idx >> 4;          // loc within tile
        const int c4 = (idx & 15) * 4;    // o chunk
        const float4 v = *reinterpret_cast<const float4*>(src + (size_t)lr * 20480 + c4);
        tile[lr][c4 + 0] = v.x; tile[lr][c4 + 1] = v.y;
        tile[lr][c4 + 2] = v.z; tile[lr][c4 + 3] = v.w;
    }
    __syncthreads();
    const int cat = m % 10;
#pragma unroll
    for (int p = 0; p < 4; ++p) {
        const int idx = p * 256 + t;
        const int o = idx >> 4;           // o within tile
        const int l4 = (idx & 15) * 4;    // loc chunk
        const float4 bv = *reinterpret_cast<const float4*>(
            bias + ((size_t)(cat * 64 + o)) * 1024 + loc0 + l4);
        float4 v;
        v.x = tile[l4 + 0][o] + bv.x;
        v.y = tile[l4 + 1][o] + bv.y;
        v.z = tile[l4 + 2][o] + bv.z;
        v.w = tile[l4 + 3][o] + bv.w;
        *reinterpret_cast<float4*>(out + ((size_t)(m * 64 + o)) * 1024 + loc0 + l4) = v;
    }
}

extern "C" void kernel_launch(void* const* d_in, const int* in_sizes, int n_in,
                              void* d_out, int out_size, void* d_ws, size_t ws_size,
                              hipStream_t stream) {
    const float* x = (const float*)d_in[0];
    const float* wgt = (const float*)d_in[1];
    const float* bias = (const float*)d_in[2];
    float* out = (float*)d_out;
    unsigned short* xT2 = (unsigned short*)d_ws;                      // 21.0 MB (+20KB slab)
    float* out_s = (float*)((char*)d_ws + OUTS_OFF_BYTES);            // 83.9 MB

    VecLocal2d_xpose<<<2560, 256, 0, stream>>>(x, xT2);
    VecLocal2d_main<<<1024, 256, 0, stream>>>(xT2, wgt, out_s);
    VecLocal2d_outT<<<5120, 256, 0, stream>>>(out_s, bias, out);
}

// Round 19
// 221.081 us; speedup vs baseline: 1.4070x; 1.0205x over previous
//
#include <hip/hip_runtime.h>
#include <hip/hip_bf16.h>

// VecLocal2d: x[320][32][32][32] f32, weight[32][32][64][288] f32, bias[10][64][1024] f32
// out[320][64][1024] f32.  Per (h,w): out[m,o] = sum_k patch[m,k]*W[o,k] + bias.
//
// R3: k permuted to k' = (dy*3+dx)*32 + c, x transposed to xT2[yx][m][c] bf16.
// A-fragments are direct 16B global loads; weight staged once to LDS; B-frags in VGPRs.
// R4 (measured): A-load batching NEUTRAL (62->65us, occ 35->18% same perf) -> not latency/TLP-bound.
// R5 (measured): outT-fusion via 4B scatter stores FAILED: WRITE 84->215MB, main 180us. Reverted.
// R6 (measured): operand swap (mfma(W,X)) + dwordx4 stores NEUTRAL (60-62us, WRITE identical)
//   -> store-issue falsified. Kept (fewer instrs).
// R7 (eleventh submit; ten infra timeouts, never measured): A-load DEDUPLICATION. Old wave
//   grid 2x2 over (m32,o32) meant wn=0/wn=1 waves loaded IDENTICAL A-fragments: 368KB/block
//   issued vs 184KB unique -> ~377MB of L2/LLC traffic, the only term big enough to explain
//   main's 62us (issue cycles ~12K of 149K/SIMD; HBM bytes only ~23us worth). New mapping:
//   each wave owns m16 x all 64 o: 9 A-loads/mt/wave (was 18), W-frags read per-kt from LDS
//   (4 ds_read_b128/kt, LDS BW ~27% of per-CU peak). Same MFMA count, same store
//   coalescing (l16-quads fill 64B lines).

typedef __attribute__((ext_vector_type(8))) short short8;
typedef __attribute__((ext_vector_type(4))) float f32x4;
typedef __attribute__((ext_vector_type(4))) unsigned short ushort4b;

#define XT2_ELEMS 10485760             // 1024 yx * 320 m * 32 c
#define ZSLAB_ELEMS 10240              // 320 m * 32 c zero slab for OOB taps
#define OUTS_OFF_BYTES 20992000        // (XT2_ELEMS + ZSLAB_ELEMS)*2 = 20,992,000 B

__device__ __forceinline__ unsigned short f2bf(float f) {
    __hip_bfloat16 b = __float2bfloat16(f);
    return __builtin_bit_cast(unsigned short, b);
}

// ---- kernel 1: x[mc][yx] f32 -> xT2[yx][mc] bf16  (10240 x 1024 transpose)
__global__ __launch_bounds__(256) void VecLocal2d_xpose(const float* __restrict__ x,
                                                        unsigned short* __restrict__ xT2) {
    __shared__ unsigned short tile[64][68];  // row = 136 B (8B-aligned for b64 writes)
    if (blockIdx.x == 0) {  // zero slab for out-of-bounds patch taps
#pragma unroll
        for (int j = 0; j < 20; ++j)
            reinterpret_cast<unsigned int*>(xT2 + XT2_ELEMS)[threadIdx.x + j * 256] = 0u;
    }
    const int mcb = blockIdx.x >> 4;   // 160 tiles over mc
    const int yxb = blockIdx.x & 15;   // 16 tiles over yx
    const int t = threadIdx.x;
    const int g = t >> 4;              // 0..15
    const int l4 = (t & 15) * 4;
#pragma unroll
    for (int p = 0; p < 4; ++p) {
        const int ml = g + p * 16;     // mc-local row
        const float4 v = *reinterpret_cast<const float4*>(
            x + (size_t)(mcb * 64 + ml) * 1024 + yxb * 64 + l4);
        ushort4b u;
        u.x = f2bf(v.x); u.y = f2bf(v.y); u.z = f2bf(v.z); u.w = f2bf(v.w);
        *reinterpret_cast<ushort4b*>(&tile[ml][l4]) = u;
    }
    __syncthreads();
#pragma unroll
    for (int p = 0; p < 4; ++p) {
        const int yl = g + p * 16;     // yx-local row
        ushort4b u;
        u.x = tile[l4 + 0][yl];
        u.y = tile[l4 + 1][yl];
        u.z = tile[l4 + 2][yl];
        u.w = tile[l4 + 3][yl];
        *reinterpret_cast<ushort4b*>(xT2 + (size_t)(yxb * 64 + yl) * 10240 + mcb * 64 + l4) = u;
    }
}

// ---- kernel 2: main GEMM per location; A-frags straight from global, no inner barriers
__global__ __launch_bounds__(256, 4) void VecLocal2d_main(const unsigned short* __restrict__ xT2,
                                                          const float* __restrict__ weight,
                                                          float* __restrict__ out_s) {
    __shared__ unsigned short wLDS[64 * 296];  // [o][k'], k' = (dy*3+dx)*32 + c, pad->296

    // XCD swizzle: neighbors in (h,w) share XCD for xT2 L2 reuse.
    const int bid = blockIdx.x;
    const int s = bid >> 7;
    const int hg = bid & 127;
    const int h = hg >> 2;
    const int w = ((hg & 3) << 3) | s;
    const int loc = h * 32 + w;

    const int tid = threadIdx.x;
    const int lane = tid & 63;
    const int wave = tid >> 6;         // R7: wave = m16 slice (0..3)
    const int quad = lane >> 4;        // k-chunk selector
    const int l16 = lane & 15;         // row selector (m for A, o for W)

    // ---- stage weight (64*288 f32, contiguous reads) -> wLDS bf16, k-permuted ----
    const float* wg = weight + (size_t)loc * 18432;
#pragma unroll
    for (int i = 0; i < 18; ++i) {
        const int f4i = tid + i * 256;
        const float4 v = reinterpret_cast<const float4*>(wg)[f4i];
        const int o = f4i / 72;
        const int kbase = (f4i - o * 72) * 4;
        const float vv[4] = {v.x, v.y, v.z, v.w};
#pragma unroll
        for (int e = 0; e < 4; ++e) {
            const int k = kbase + e;       // original k = c*9 + r
            const int c = k / 9;
            const int r = k - c * 9;
            wLDS[o * 296 + r * 32 + c] = f2bf(vv[e]);
        }
    }

    // ---- 9 neighbor base offsets (block-uniform -> SGPRs); OOB -> zero slab ----
    int base[9];
#pragma unroll
    for (int dy = 0; dy < 3; ++dy)
#pragma unroll
        for (int dx = 0; dx < 3; ++dx) {
            const int y = h - 1 + dy;
            const int xc = w - 1 + dx;
            const bool valid = ((unsigned)y < 32u) && ((unsigned)xc < 32u);
            base[dy * 3 + dx] = valid ? (y * 32 + xc) * 10240 : XT2_ELEMS;
        }

    __syncthreads();

    // R7: per-lane W base: row o = tni*16 + l16, k-chunk quad*8 (read inside loop).
    const unsigned short* wl = &wLDS[l16 * 296 + quad * 8];
    const int laneA = (wave * 16 + l16) * 32 + quad * 8;  // + mt*2048
    float* os = out_s + (size_t)loc * 20480;

    for (int mt = 0; mt < 5; ++mt) {
        const int moff = laneA + mt * 2048;
        f32x4 acc[4] = {};
#pragma unroll
        for (int kt = 0; kt < 9; ++kt) {
            const short8 a = *reinterpret_cast<const short8*>(xT2 + base[kt] + moff);
#pragma unroll
            for (int tni = 0; tni < 4; ++tni) {
                const short8 b = *reinterpret_cast<const short8*>(wl + tni * (16 * 296) + kt * 32);
                acc[tni] = __builtin_amdgcn_mfma_f32_16x16x32_bf16(b, a, acc[tni], 0, 0, 0);
            }
        }

        // Swapped-D: col(=m_local)=l16, row(=o_local)=quad*4+r. One dwordx4 per tni;
        // lanes {l16, l16+16, l16+32, l16+48} complete one 64B line of row m.
        const int m = mt * 64 + wave * 16 + l16;
#pragma unroll
        for (int tni = 0; tni < 4; ++tni) {
            *reinterpret_cast<f32x4*>(&os[m * 64 + tni * 16 + quad * 4]) = acc[tni];
        }
    }
}

// ---- kernel 3: out_s[loc][m*64+o] -> out[(m*64+o)*1024+loc], bias fused.
__global__ __launch_bounds__(256) void VecLocal2d_outT(const float* __restrict__ out_s,
                                                       const float* __restrict__ bias,
                                                       float* __restrict__ out) {
    __shared__ float tile[64][65];
    const int m = blockIdx.x >> 4;
    const int loc0 = (blockIdx.x & 15) * 64;
    const int t = threadIdx.x;
    const float* src = out_s + (size_t)loc0 * 20480 + m * 64;
#pragma unroll
    for (int p = 0; p < 4; ++p) {
        const int idx = p * 256 + t;
        const int lr = idx >> 4;          // loc within tile
        const int c4 = (idx & 15) * 4;    // o chunk
        const float4 v = *reinterpret_cast<const float4*>(src + (size_t)lr * 20480 + c4);
        tile[lr][c4 + 0] = v.x; tile[lr][c4 + 1] = v.y;
        tile[lr][c4 + 2] = v.z; tile[lr][c4 + 3] = v.w;
    }
    __syncthreads();
    const int cat = m % 10;
#pragma unroll
    for (int p = 0; p < 4; ++p) {
        const int idx = p * 256 + t;
        const int o = idx >> 4;           // o within tile
        const int l4 = (idx & 15) * 4;    // loc chunk
        const float4 bv = *reinterpret_cast<const float4*>(
            bias + ((size_t)(cat * 64 + o)) * 1024 + loc0 + l4);
        float4 v;
        v.x = tile[l4 + 0][o] + bv.x;
        v.y = tile[l4 + 1][o] + bv.y;
        v.z = tile[l4 + 2][o] + bv.z;
        v.w = tile[l4 + 3][o] + bv.w;
        *reinterpret_cast<float4*>(out + ((size_t)(m * 64 + o)) * 1024 + loc0 + l4) = v;
    }
}

extern "C" void kernel_launch(void* const* d_in, const int* in_sizes, int n_in,
                              void* d_out, int out_size, void* d_ws, size_t ws_size,
                              hipStream_t stream) {
    const float* x = (const float*)d_in[0];
    const float* wgt = (const float*)d_in[1];
    const float* bias = (const float*)d_in[2];
    float* out = (float*)d_out;
    unsigned short* xT2 = (unsigned short*)d_ws;                      // 21.0 MB (+20KB slab)
    float* out_s = (float*)((char*)d_ws + OUTS_OFF_BYTES);            // 83.9 MB

    VecLocal2d_xpose<<<2560, 256, 0, stream>>>(x, xT2);
    VecLocal2d_main<<<1024, 256, 0, stream>>>(xT2, wgt, out_s);
    VecLocal2d_outT<<<5120, 256, 0, stream>>>(out_s, bias, out);
}

// Round 20
// 213.378 us; speedup vs baseline: 1.4578x; 1.0361x over previous
//
#include <hip/hip_runtime.h>
#include <hip/hip_bf16.h>

// VecLocal2d: x[320][32][32][32] f32, weight[32][32][64][288] f32, bias[10][64][1024] f32
// out[320][64][1024] f32.  Per (h,w): out[m,o] = sum_k patch[m,k]*W[o,k] + bias.
//
// R3: k permuted to k' = (dy*3+dx)*32 + c, x transposed to xT2[yx][m][c] bf16.
// R4 (measured): A-load batching NEUTRAL (62->65us, occ 35->18% same perf) -> not latency/TLP-bound.
// R5 (measured): outT-fusion via 4B scatter stores FAILED: WRITE 84->215MB, main 180us. Reverted.
// R6 (measured): operand swap (mfma(W,X)) + dwordx4 stores NEUTRAL -> store-issue falsified. Kept.
// R7 (measured): A-load dedup (wave owns m16 x all 64 o, W re-read from LDS per kt):
//   main 60-62 -> 57-58us, total 221us. Small win; cache-dup was minor term. Kept.
//   Bank conflicts 1.47M->4.13M (~3% of cycles) from per-kt W ds_reads - acceptable.
// R8 (this round): BF16 out_s. The 168MB f32 out_s round-trip exists only to buffer the
//   output transpose; accumulation stays f32, only the staging is rounded to bf16
//   (adds <=0.4% rel, inputs already bf16). main stores acc as ushort4 (each wave's 4
//   tni stores cover contiguous 128B per m-row -> same-block write-combining, no R5
//   cross-block partial lines); outT reads bf16, adds bias in f32, writes f32 out.
//   Round-trip 168 -> 84MB. Predict: main WRITE 82->41MB, dur -4-8us; outT -8-12us;
//   absmax 0.03125 -> ~0.05 (revert if fail). Total 221 -> ~200-208us.

typedef __attribute__((ext_vector_type(8))) short short8;
typedef __attribute__((ext_vector_type(4))) float f32x4;
typedef __attribute__((ext_vector_type(4))) unsigned short ushort4b;

#define XT2_ELEMS 10485760             // 1024 yx * 320 m * 32 c
#define ZSLAB_ELEMS 10240              // 320 m * 32 c zero slab for OOB taps
#define OUTS_OFF_BYTES 20992000        // (XT2_ELEMS + ZSLAB_ELEMS)*2 = 20,992,000 B

__device__ __forceinline__ unsigned short f2bf(float f) {
    __hip_bfloat16 b = __float2bfloat16(f);
    return __builtin_bit_cast(unsigned short, b);
}

__device__ __forceinline__ float bf2f(unsigned short u) {
    const unsigned int x = ((unsigned int)u) << 16;
    return __builtin_bit_cast(float, x);
}

// ---- kernel 1: x[mc][yx] f32 -> xT2[yx][mc] bf16  (10240 x 1024 transpose)
__global__ __launch_bounds__(256) void VecLocal2d_xpose(const float* __restrict__ x,
                                                        unsigned short* __restrict__ xT2) {
    __shared__ unsigned short tile[64][68];  // row = 136 B (8B-aligned for b64 writes)
    if (blockIdx.x == 0) {  // zero slab for out-of-bounds patch taps
#pragma unroll
        for (int j = 0; j < 20; ++j)
            reinterpret_cast<unsigned int*>(xT2 + XT2_ELEMS)[threadIdx.x + j * 256] = 0u;
    }
    const int mcb = blockIdx.x >> 4;   // 160 tiles over mc
    const int yxb = blockIdx.x & 15;   // 16 tiles over yx
    const int t = threadIdx.x;
    const int g = t >> 4;              // 0..15
    const int l4 = (t & 15) * 4;
#pragma unroll
    for (int p = 0; p < 4; ++p) {
        const int ml = g + p * 16;     // mc-local row
        const float4 v = *reinterpret_cast<const float4*>(
            x + (size_t)(mcb * 64 + ml) * 1024 + yxb * 64 + l4);
        ushort4b u;
        u.x = f2bf(v.x); u.y = f2bf(v.y); u.z = f2bf(v.z); u.w = f2bf(v.w);
        *reinterpret_cast<ushort4b*>(&tile[ml][l4]) = u;
    }
    __syncthreads();
#pragma unroll
    for (int p = 0; p < 4; ++p) {
        const int yl = g + p * 16;     // yx-local row
        ushort4b u;
        u.x = tile[l4 + 0][yl];
        u.y = tile[l4 + 1][yl];
        u.z = tile[l4 + 2][yl];
        u.w = tile[l4 + 3][yl];
        *reinterpret_cast<ushort4b*>(xT2 + (size_t)(yxb * 64 + yl) * 10240 + mcb * 64 + l4) = u;
    }
}

// ---- kernel 2: main GEMM per location; A-frags straight from global, no inner barriers
__global__ __launch_bounds__(256, 4) void VecLocal2d_main(const unsigned short* __restrict__ xT2,
                                                          const float* __restrict__ weight,
                                                          unsigned short* __restrict__ out_s) {
    __shared__ unsigned short wLDS[64 * 296];  // [o][k'], k' = (dy*3+dx)*32 + c, pad->296

    // XCD swizzle: neighbors in (h,w) share XCD for xT2 L2 reuse.
    const int bid = blockIdx.x;
    const int s = bid >> 7;
    const int hg = bid & 127;
    const int h = hg >> 2;
    const int w = ((hg & 3) << 3) | s;
    const int loc = h * 32 + w;

    const int tid = threadIdx.x;
    const int lane = tid & 63;
    const int wave = tid >> 6;         // R7: wave = m16 slice (0..3)
    const int quad = lane >> 4;        // k-chunk selector
    const int l16 = lane & 15;         // row selector (m for A, o for W)

    // ---- stage weight (64*288 f32, contiguous reads) -> wLDS bf16, k-permuted ----
    const float* wg = weight + (size_t)loc * 18432;
#pragma unroll
    for (int i = 0; i < 18; ++i) {
        const int f4i = tid + i * 256;
        const float4 v = reinterpret_cast<const float4*>(wg)[f4i];
        const int o = f4i / 72;
        const int kbase = (f4i - o * 72) * 4;
        const float vv[4] = {v.x, v.y, v.z, v.w};
#pragma unroll
        for (int e = 0; e < 4; ++e) {
            const int k = kbase + e;       // original k = c*9 + r
            const int c = k / 9;
            const int r = k - c * 9;
            wLDS[o * 296 + r * 32 + c] = f2bf(vv[e]);
        }
    }

    // ---- 9 neighbor base offsets (block-uniform -> SGPRs); OOB -> zero slab ----
    int base[9];
#pragma unroll
    for (int dy = 0; dy < 3; ++dy)
#pragma unroll
        for (int dx = 0; dx < 3; ++dx) {
            const int y = h - 1 + dy;
            const int xc = w - 1 + dx;
            const bool valid = ((unsigned)y < 32u) && ((unsigned)xc < 32u);
            base[dy * 3 + dx] = valid ? (y * 32 + xc) * 10240 : XT2_ELEMS;
        }

    __syncthreads();

    // R7: per-lane W base: row o = tni*16 + l16, k-chunk quad*8 (read inside loop).
    const unsigned short* wl = &wLDS[l16 * 296 + quad * 8];
    const int laneA = (wave * 16 + l16) * 32 + quad * 8;  // + mt*2048
    unsigned short* os = out_s + (size_t)loc * 20480;

    for (int mt = 0; mt < 5; ++mt) {
        const int moff = laneA + mt * 2048;
        f32x4 acc[4] = {};
#pragma unroll
        for (int kt = 0; kt < 9; ++kt) {
            const short8 a = *reinterpret_cast<const short8*>(xT2 + base[kt] + moff);
#pragma unroll
            for (int tni = 0; tni < 4; ++tni) {
                const short8 b = *reinterpret_cast<const short8*>(wl + tni * (16 * 296) + kt * 32);
                acc[tni] = __builtin_amdgcn_mfma_f32_16x16x32_bf16(b, a, acc[tni], 0, 0, 0);
            }
        }

        // Swapped-D: col(=m_local)=l16, row(=o_local)=quad*4+r.
        // R8: round acc to bf16, one ushort4 (8B) store per tni; the wave's 4 tni
        // stores cover a contiguous 128B per m-row (same-block write-combining).
        const int m = mt * 64 + wave * 16 + l16;
#pragma unroll
        for (int tni = 0; tni < 4; ++tni) {
            ushort4b u;
            u.x = f2bf(acc[tni][0]);
            u.y = f2bf(acc[tni][1]);
            u.z = f2bf(acc[tni][2]);
            u.w = f2bf(acc[tni][3]);
            *reinterpret_cast<ushort4b*>(&os[m * 64 + tni * 16 + quad * 4]) = u;
        }
    }
}

// ---- kernel 3: out_s bf16 [loc][m*64+o] -> out f32 [(m*64+o)*1024+loc], bias fused.
__global__ __launch_bounds__(256) void VecLocal2d_outT(const unsigned short* __restrict__ out_s,
                                                       const float* __restrict__ bias,
                                                       float* __restrict__ out) {
    __shared__ float tile[64][65];
    const int m = blockIdx.x >> 4;
    const int loc0 = (blockIdx.x & 15) * 64;
    const int t = threadIdx.x;
    const unsigned short* src = out_s + (size_t)loc0 * 20480 + m * 64;
#pragma unroll
    for (int p = 0; p < 4; ++p) {
        const int idx = p * 256 + t;
        const int lr = idx >> 4;          // loc within tile
        const int c4 = (idx & 15) * 4;    // o chunk
        const ushort4b v = *reinterpret_cast<const ushort4b*>(src + (size_t)lr * 20480 + c4);
        tile[lr][c4 + 0] = bf2f(v.x); tile[lr][c4 + 1] = bf2f(v.y);
        tile[lr][c4 + 2] = bf2f(v.z); tile[lr][c4 + 3] = bf2f(v.w);
    }
    __syncthreads();
    const int cat = m % 10;
#pragma unroll
    for (int p = 0; p < 4; ++p) {
        const int idx = p * 256 + t;
        const int o = idx >> 4;           // o within tile
        const int l4 = (idx & 15) * 4;    // loc chunk
        const float4 bv = *reinterpret_cast<const float4*>(
            bias + ((size_t)(cat * 64 + o)) * 1024 + loc0 + l4);
        float4 v;
        v.x = tile[l4 + 0][o] + bv.x;
        v.y = tile[l4 + 1][o] + bv.y;
        v.z = tile[l4 + 2][o] + bv.z;
        v.w = tile[l4 + 3][o] + bv.w;
        *reinterpret_cast<float4*>(out + ((size_t)(m * 64 + o)) * 1024 + loc0 + l4) = v;
    }
}

extern "C" void kernel_launch(void* const* d_in, const int* in_sizes, int n_in,
                              void* d_out, int out_size, void* d_ws, size_t ws_size,
                              hipStream_t stream) {
    const float* x = (const float*)d_in[0];
    const float* wgt = (const float*)d_in[1];
    const float* bias = (const float*)d_in[2];
    float* out = (float*)d_out;
    unsigned short* xT2 = (unsigned short*)d_ws;                           // 21.0 MB (+20KB slab)
    unsigned short* out_s = (unsigned short*)((char*)d_ws + OUTS_OFF_BYTES); // 41.9 MB bf16

    VecLocal2d_xpose<<<2560, 256, 0, stream>>>(x, xT2);
    VecLocal2d_main<<<1024, 256, 0, stream>>>(xT2, wgt, out_s);
    VecLocal2d_outT<<<5120, 256, 0, stream>>>(out_s, bias, out);
}